// Round 2
// baseline (17565.091 us; speedup 1.0000x reference)
//
#include <hip/hip_runtime.h>
#include <cstdint>
#include <cstddef>

// Problem constants
#define BB   64
#define TT   512
#define HH   500
#define G4H  2000   // 4*H
#define KPAD 512    // recurrent K padded 500 -> 512
#define TCH  64     // timesteps per phase
#define D1P  1024   // layer-1 input dim padded 1000 -> 1024
#define NPAD 2048   // gate rows padded 2000 -> 2048 (= 32 blocks * 64 rows)
#define UPB  16     // hidden units per recurrence block
#define NB2  32     // recurrence blocks per direction
#define WSL2 (32 * 64 * 512)   // per-dir fp16 recurrent weight slice elements

typedef _Float16 v8h __attribute__((ext_vector_type(8)));
typedef _Float16 v4h __attribute__((ext_vector_type(4)));
typedef float    v4f __attribute__((ext_vector_type(4)));

union F16x8 {
    unsigned long long u[2];
    float4 f4;
    v8h h;
};
union H16B { _Float16 f; unsigned short u; };

__device__ __forceinline__ float sigm(float x) { return 1.f / (1.f + __expf(-x)); }
__device__ __forceinline__ float tanh_fast(float x) {
    float e = __expf(2.f * x);
    return 1.f - 2.f / (e + 1.f);
}

// async global->LDS, 16B per lane. LDS dest must be wave-linear (base + lane*16).
__device__ __forceinline__ void gload_lds16(const _Float16* src, _Float16* dst) {
    __builtin_amdgcn_global_load_lds(
        (const __attribute__((address_space(1))) void*)src,
        (__attribute__((address_space(3))) void*)dst, 16, 0, 0);
}

// Row permutation shared by all gate-side tensors:
//   n' = bi*64 + g*16 + j  <->  original gate row g*500 + (bi*16 + j)
//   valid iff u = bi*16 + j < 500 (only bi=31, j>=4 invalid -> zero)

// ---- prep: W_hh [2000][500] fp32 -> fp16 slices [ld][bi(32)][r(64)][k(512)] ----
__global__ __launch_bounds__(256) void pad_whh16_kernel(
    const float* __restrict__ w0, const float* __restrict__ w1,
    const float* __restrict__ w2, const float* __restrict__ w3,
    _Float16* __restrict__ dst)
{
    int idx = blockIdx.x * 256 + threadIdx.x;   // exactly 4*32*64*512 threads
    int k = idx & 511;
    int t = idx >> 9;
    int r = t & 63;  t >>= 6;
    int bi = t & 31;
    int ld = t >> 5;
    int g = r >> 4, j = r & 15;
    int u = bi * UPB + j;
    const float* src = (ld == 0) ? w0 : (ld == 1) ? w1 : (ld == 2) ? w2 : w3;
    float val = (u < HH && k < HH) ? src[(size_t)(g * HH + u) * HH + k] : 0.f;
    dst[idx] = (_Float16)val;
}

// ---- prep: W_ih -> fp16, rows permuted, [dir][NPAD][1<<kshift] ----
__global__ __launch_bounds__(256) void pad_wih16_kernel(
    const float* __restrict__ wf, const float* __restrict__ wb,
    _Float16* __restrict__ dst, int ksrc, int kshift)
{
    int idx = blockIdx.x * 256 + threadIdx.x;
    int kdst = 1 << kshift;
    int k = idx & (kdst - 1);
    int n = (idx >> kshift) & (NPAD - 1);
    int d = idx >> (kshift + 11);
    int bi = n >> 6, r = n & 63, g = r >> 4, j = r & 15;
    int u = bi * UPB + j;
    const float* src = d ? wb : wf;
    float v = (u < HH && k < ksrc) ? src[(size_t)(g * HH + u) * ksrc + k] : 0.f;
    dst[idx] = (_Float16)v;
}

// ---- prep: bias -> permuted fp32 [4][NPAD] ----
__global__ __launch_bounds__(256) void bias_perm_kernel(
    const float* __restrict__ b0f_, const float* __restrict__ b0b_,
    const float* __restrict__ b1f_, const float* __restrict__ b1b_,
    float* __restrict__ dst)
{
    int idx = blockIdx.x * 256 + threadIdx.x;   // 4*2048
    int n = idx & (NPAD - 1);
    int ld = idx >> 11;
    int bi = n >> 6, r = n & 63, g = r >> 4, j = r & 15;
    int u = bi * UPB + j;
    const float* src = (ld == 0) ? b0f_ : (ld == 1) ? b0b_ : (ld == 2) ? b1f_ : b1b_;
    dst[idx] = (u < HH) ? src[g * HH + u] : 0.f;
}

// ---- prep: seqs fp32 -> fp16 (4 elems/thread) ----
__global__ __launch_bounds__(256) void f32to16x4_kernel(
    const float* __restrict__ src, _Float16* __restrict__ dst)
{
    int idx = blockIdx.x * 256 + threadIdx.x;
    float4 v = ((const float4*)src)[idx];
    v4h o;
    o[0] = (_Float16)v.x; o[1] = (_Float16)v.y;
    o[2] = (_Float16)v.z; o[3] = (_Float16)v.w;
    ((v4h*)dst)[idx] = o;
}

// ---- MFMA input-projection GEMM for one 64-timestep chunk, both dirs ----
// gates[dir][b][tl][n'] = sum_k A16[b][t0+tl][k] * W16[dir][n'][k] + bias[n']
#define BM 128
#define BN 128
#define BKG 64

__global__ __launch_bounds__(256, 2) void gemm16_kernel(
    const _Float16* __restrict__ A16, int K,
    const _Float16* __restrict__ W16,     // [2][NPAD][K], rows permuted
    const float* __restrict__ bf_, const float* __restrict__ bb_,
    float* __restrict__ gates, int t0f, int t0b)
{
    const int dir = blockIdx.z;
    const int t0  = dir ? t0b : t0f;
    const _Float16* W = W16 + (size_t)dir * NPAD * K;
    const float* bias = dir ? bb_ : bf_;
    const int mtile = blockIdx.x;     // 0..31
    const int ntile = blockIdx.y;     // 0..15
    const int tid  = threadIdx.x;
    const int lane = tid & 63;
    const int wv = __builtin_amdgcn_readfirstlane(tid >> 6);
    const int wm = wv >> 1, wn = wv & 1;

    __shared__ _Float16 Asm[BM * BKG];   // 16 KB
    __shared__ _Float16 Bsm[BN * BKG];   // 16 KB

    const _Float16* aPtr[4];
    const _Float16* bPtr[4];
    #pragma unroll
    for (int it = 0; it < 4; ++it) {
        const int s = tid + it * 256;
        const int row = s >> 3;
        const int kswz = ((s ^ row) & 7) << 3;       // (slot8 ^ (row&7)) * 8
        const int rg = mtile * BM + row;
        const int b = rg >> 6;
        const int t = t0 + (rg & 63);
        aPtr[it] = A16 + (size_t)(b * TT + t) * K + kswz;
        bPtr[it] = W + (size_t)(ntile * BN + row) * K + kswz;
    }

    v4f acc[4][4];
    #pragma unroll
    for (int mt = 0; mt < 4; ++mt)
        #pragma unroll
        for (int nt = 0; nt < 4; ++nt) acc[mt][nt] = (v4f)(0.f);

    for (int k0 = 0; k0 < K; k0 += BKG) {
        #pragma unroll
        for (int it = 0; it < 4; ++it) {
            gload_lds16(aPtr[it] + k0, &Asm[(tid + it * 256) * 8]);
            gload_lds16(bPtr[it] + k0, &Bsm[(tid + it * 256) * 8]);
        }
        __syncthreads();
        #pragma unroll
        for (int kk = 0; kk < 2; ++kk) {
            v8h af[4], bw[4];
            #pragma unroll
            for (int mt = 0; mt < 4; ++mt) {
                const int row = wm * 64 + mt * 16 + (lane & 15);
                const int slot = (kk * 4 + (lane >> 4)) ^ (row & 7);
                af[mt] = *(const v8h*)&Asm[row * BKG + slot * 8];
            }
            #pragma unroll
            for (int nt = 0; nt < 4; ++nt) {
                const int row = wn * 64 + nt * 16 + (lane & 15);
                const int slot = (kk * 4 + (lane >> 4)) ^ (row & 7);
                bw[nt] = *(const v8h*)&Bsm[row * BKG + slot * 8];
            }
            #pragma unroll
            for (int mt = 0; mt < 4; ++mt)
                #pragma unroll
                for (int nt = 0; nt < 4; ++nt)
                    acc[mt][nt] = __builtin_amdgcn_mfma_f32_16x16x32_f16(
                        af[mt], bw[nt], acc[mt][nt], 0, 0, 0);
        }
        __syncthreads();
    }

    // epilogue: D frag (16x16): col = lane&15, row = (lane>>4)*4 + i
    float* gout = gates + (size_t)dir * (BB * TCH * NPAD);
    const int colBase = ntile * BN + wn * 64 + (lane & 15);
    const int rowBase = mtile * BM + wm * 64 + ((lane >> 4) * 4);
    #pragma unroll
    for (int nt = 0; nt < 4; ++nt) {
        const int n = colBase + nt * 16;
        const float bv = bias[n];
        #pragma unroll
        for (int mt = 0; mt < 4; ++mt) {
            const int r = rowBase + mt * 16;
            const int b = r >> 6;
            const int tl = r & 63;
            float* gp = gout + (size_t)(b * TCH + tl) * NPAD + n;
            #pragma unroll
            for (int i = 0; i < 4; ++i)
                gp[(size_t)i * NPAD] = acc[mt][nt][i] + bv;
        }
    }
}

// ---- persistent MFMA recurrence: 64 blocks (32/dir), 16 units/block ----
// Wave w computes gate w for all 16 units: C[64b x 64row] = h16 @ Wslice^T,
// per wave rows w*16..+15, full K=512, 64 MFMAs, no k-split reduction.
// Cell state (c, h_prev) lives in registers of thread (b = tid>>2, q = tid&3)
// which owns units u0+q*4..+3. Only exchange: C tile via LDS.
// Barrier: flag-array (one 64B-spread flag per block, parallel poll).
__global__ __launch_bounds__(256, 1) void lstm_phase_kernel(
    const float*    __restrict__ gates,   // [dir][B][TCH][NPAD]
    const _Float16* __restrict__ whh16,   // layer base: [dir][bi][64][512]
    const int*      __restrict__ lengths,
    _Float16* __restrict__ h16,           // [dir][2][B][512] fp16
    float*    __restrict__ cbuf,          // [dir][B][KPAD] fp32
    void*     __restrict__ yout, int y_ld, int yF16,
    int s0, int gstep0,
    unsigned int* __restrict__ flags)     // [64] x 16 u32 (64B spacing)
{
    const int tid  = threadIdx.x;
    const int dir  = (blockIdx.x >= NB2) ? 1 : 0;
    const int bi   = blockIdx.x - dir * NB2;
    const int u0   = bi * UPB;
    const int lane = tid & 63;
    const int w    = __builtin_amdgcn_readfirstlane(tid >> 6);  // wave = gate

    __shared__ float Ct[64][65];   // [gate-row r][batch m], +1 pad

    // B-frags resident all phase: rows r = w*16 + (lane&15), k = kt*32 + (lane>>4)*8
    v8h bfr[16];
    {
        const _Float16* wb = whh16 + (size_t)dir * WSL2
            + ((size_t)(bi * 64 + w * 16 + (lane & 15))) * 512 + ((lane >> 4) * 8);
        #pragma unroll
        for (int kt = 0; kt < 16; ++kt) {
            F16x8 f; f.f4 = *(const float4*)(wb + kt * 32);
            bfr[kt] = f.h;
        }
    }

    // cell ownership: thread = (batch eb, unit quad q)
    const int eb = tid >> 2;
    const int q  = tid & 3;
    const int uu = u0 + q * 4;
    const int len_r = lengths[eb];
    const bool uvalid = (uu < HH);   // quad fully valid or fully invalid (500%4==0)

    float cst[4], hpv[4];
    #pragma unroll
    for (int j = 0; j < 4; ++j)
        cst[j] = cbuf[(size_t)(dir * BB + eb) * KPAD + uu + j];
    #pragma unroll
    for (int j = 0; j < 4; ++j)   // phase start is always even parity -> buffer 0
        hpv[j] = (float)h16[((size_t)(dir * 2 + 0) * BB + eb) * 512 + uu + j];

    const float* gbase = gates + (size_t)dir * (BB * TCH * NPAD) + bi * 64 + q * 4;

    for (int sl = 0; sl < TCH; ++sl) {
        const int s   = s0 + sl;
        const int par = s & 1;
        const int t   = dir ? (TT - 1 - s) : s;
        const int tl  = dir ? (TCH - 1 - sl) : sl;

        // gate-x loads (plain; dense 64B per (b,t,gate) across the q-quads)
        float4 gx[4];
        {
            const float* gp = gbase + (size_t)(eb * TCH + tl) * NPAD;
            #pragma unroll
            for (int g = 0; g < 4; ++g) gx[g] = *(const float4*)(gp + g * 16);
        }

        // A-frag loads (coherent b64 atomics) + 64 MFMAs, full K per wave
        v4f acc[4];
        #pragma unroll
        for (int mt = 0; mt < 4; ++mt) acc[mt] = (v4f)(0.f);
        {
            const char* hb = (const char*)(h16 + (size_t)(dir * 2 + par) * BB * 512);
            const int rowoff = (lane & 15) * 512 + ((lane >> 4) * 8);
            #pragma unroll
            for (int kt = 0; kt < 16; ++kt) {
                F16x8 av[4];
                #pragma unroll
                for (int mt = 0; mt < 4; ++mt) {
                    const size_t off = ((size_t)(mt * 16) * 512 + rowoff + kt * 32) * 2;
                    const unsigned long long* p = (const unsigned long long*)(hb + off);
                    av[mt].u[0] = __hip_atomic_load(p,     __ATOMIC_RELAXED, __HIP_MEMORY_SCOPE_AGENT);
                    av[mt].u[1] = __hip_atomic_load(p + 1, __ATOMIC_RELAXED, __HIP_MEMORY_SCOPE_AGENT);
                }
                #pragma unroll
                for (int mt = 0; mt < 4; ++mt)
                    acc[mt] = __builtin_amdgcn_mfma_f32_16x16x32_f16(
                        av[mt].h, bfr[kt], acc[mt], 0, 0, 0);
            }
        }

        // C tile -> LDS. D frag: col(lane&15)=W row within 16, row=(lane>>4)*4+i=batch.
        // Safe without a pre-sync: previous iter's release barrier guarantees all
        // waves finished their epilogue Ct reads.
        #pragma unroll
        for (int mt = 0; mt < 4; ++mt)
            #pragma unroll
            for (int i = 0; i < 4; ++i)
                Ct[w * 16 + (lane & 15)][mt * 16 + (lane >> 4) * 4 + i] = acc[mt][i];
        __syncthreads();

        // epilogue: 4 cells per thread
        const bool msk = (t < len_r);
        float hnv[4];
        #pragma unroll
        for (int j = 0; j < 4; ++j) {
            const int r0 = q * 4 + j;
            const float p0 = Ct[r0][eb]      + ((const float*)&gx[0])[j];
            const float p1 = Ct[16 + r0][eb] + ((const float*)&gx[1])[j];
            const float p2 = Ct[32 + r0][eb] + ((const float*)&gx[2])[j];
            const float p3 = Ct[48 + r0][eb] + ((const float*)&gx[3])[j];
            const float ig = sigm(p0);
            const float fg = sigm(p1);
            const float gg = tanh_fast(p2);
            const float og = sigm(p3);
            const float cn = fg * cst[j] + ig * gg;
            const float hn = og * tanh_fast(cn);
            cst[j] = msk ? cn : cst[j];
            hpv[j] = msk ? hn : hpv[j];
            hnv[j] = msk ? hn : 0.f;
        }

        // y store (dense 16B per thread; 4 threads/b -> 64B line)
        if (uvalid) {
            const size_t yoff = ((size_t)eb * TT + t) * y_ld + dir * HH + uu;
            if (yF16) {
                v4h o;
                #pragma unroll
                for (int j = 0; j < 4; ++j) o[j] = (_Float16)hnv[j];
                *(v4h*)((_Float16*)yout + yoff) = o;
            } else {
                float4 o = make_float4(hnv[0], hnv[1], hnv[2], hnv[3]);
                *(float4*)((float*)yout + yoff) = o;
            }
        }

        // publish h quad as one coherent b64 store
        {
            H16B h0, h1, h2, h3;
            h0.f = (_Float16)hpv[0]; h1.f = (_Float16)hpv[1];
            h2.f = (_Float16)hpv[2]; h3.f = (_Float16)hpv[3];
            const unsigned long long pv =
                  (unsigned long long)h0.u
                | ((unsigned long long)h1.u << 16)
                | ((unsigned long long)h2.u << 32)
                | ((unsigned long long)h3.u << 48);
            unsigned long long* dst = (unsigned long long*)
                (h16 + ((size_t)(dir * 2 + (par ^ 1)) * BB + eb) * 512 + uu);
            __hip_atomic_store(dst, pv, __ATOMIC_RELAXED, __HIP_MEMORY_SCOPE_AGENT);
        }

        __syncthreads();   // drains publish/y stores (vmcnt 0) + LDS reads

        // flag-array barrier: arrival = store step number to own 64B-spread flag;
        // wave 0 polls all 32 flags of this dir in parallel.
        const unsigned int tgt = (unsigned int)(gstep0 + sl + 1);
        if (tid == 0)
            __hip_atomic_store(&flags[(dir * NB2 + bi) * 16], tgt,
                               __ATOMIC_RELAXED, __HIP_MEMORY_SCOPE_AGENT);
        if (tid < 64) {
            const int fi = lane & 31;
            for (;;) {
                unsigned int v = __hip_atomic_load(&flags[(dir * NB2 + fi) * 16],
                                                   __ATOMIC_RELAXED, __HIP_MEMORY_SCOPE_AGENT);
                if (__all(v >= tgt)) break;
                __builtin_amdgcn_s_sleep(2);
            }
        }
        __syncthreads();   // release whole block
    }

    // persist c (fp32) for next phase
    #pragma unroll
    for (int j = 0; j < 4; ++j)
        cbuf[(size_t)(dir * BB + eb) * KPAD + uu + j] = cst[j];
}

extern "C" void kernel_launch(void* const* d_in, const int* in_sizes, int n_in,
                              void* d_out, int out_size, void* d_ws, size_t ws_size,
                              hipStream_t stream)
{
    (void)in_sizes; (void)n_in; (void)out_size; (void)ws_size;

    const float* seqs    = (const float*)d_in[0];
    const int*   lengths = (const int*)  d_in[1];
    const float* W_ih0f  = (const float*)d_in[2];
    const float* W_hh0f  = (const float*)d_in[3];
    const float* b0f     = (const float*)d_in[4];
    const float* W_ih0b  = (const float*)d_in[5];
    const float* W_hh0b  = (const float*)d_in[6];
    const float* b0b     = (const float*)d_in[7];
    const float* W_ih1f  = (const float*)d_in[8];
    const float* W_hh1f  = (const float*)d_in[9];
    const float* b1f     = (const float*)d_in[10];
    const float* W_ih1b  = (const float*)d_in[11];
    const float* W_hh1b  = (const float*)d_in[12];
    const float* b1b     = (const float*)d_in[13];

    char* ws = (char*)d_ws;
    const size_t SZ_GATES = (size_t)2 * BB * TCH * NPAD * 4;  //  67,108,864
    const size_t SZ_SEQ16 = (size_t)BB * TT * 512 * 2;        //  33,554,432
    const size_t SZ_OUT16 = (size_t)BB * TT * D1P * 2;        //  67,108,864
    const size_t SZ_WIH0  = (size_t)2 * NPAD * 512 * 2;       //   4,194,304
    const size_t SZ_WIH1  = (size_t)2 * NPAD * D1P * 2;       //   8,388,608
    const size_t SZ_WHH16 = (size_t)4 * WSL2 * 2;             //   8,388,608
    const size_t SZ_BPERM = (size_t)4 * NPAD * 4;             //      32,768
    const size_t SZ_H16   = (size_t)2 * 2 * BB * 512 * 2;     //     262,144
    const size_t SZ_CBUF  = (size_t)2 * BB * KPAD * 4;        //     262,144
    const size_t SZ_FLAGS = (size_t)64 * 16 * 4;              //       4,096

    size_t off = 0;
    float*     gatesc = (float*)(ws + off);     off += SZ_GATES;
    _Float16*  seq16  = (_Float16*)(ws + off);  off += SZ_SEQ16;
    _Float16*  out16  = (_Float16*)(ws + off);  off += SZ_OUT16;
    _Float16*  wih016 = (_Float16*)(ws + off);  off += SZ_WIH0;
    _Float16*  wih116 = (_Float16*)(ws + off);  off += SZ_WIH1;
    _Float16*  whh16  = (_Float16*)(ws + off);  off += SZ_WHH16;
    float*     bperm  = (float*)(ws + off);     off += SZ_BPERM;
    _Float16*  h16    = (_Float16*)(ws + off);  off += SZ_H16;
    float*     cbuf   = (float*)(ws + off);     off += SZ_CBUF;
    unsigned int* flags = (unsigned int*)(ws + off);  off += SZ_FLAGS;

    // one-time prep
    pad_whh16_kernel<<<16384, 256, 0, stream>>>(W_hh0f, W_hh0b, W_hh1f, W_hh1b, whh16);
    pad_wih16_kernel<<<8192,  256, 0, stream>>>(W_ih0f, W_ih0b, wih016, 512, 9);
    pad_wih16_kernel<<<16384, 256, 0, stream>>>(W_ih1f, W_ih1b, wih116, 1000, 10);
    bias_perm_kernel<<<32,    256, 0, stream>>>(b0f, b0b, b1f, b1b, bperm);
    f32to16x4_kernel<<<16384, 256, 0, stream>>>(seqs, seq16);
    hipMemsetAsync(out16, 0, SZ_OUT16, stream);   // zeros k-pad cols 1000..1023
    hipMemsetAsync(flags, 0, SZ_FLAGS, stream);

    for (int layer = 0; layer < 2; ++layer) {
        hipMemsetAsync(h16, 0, SZ_H16, stream);
        hipMemsetAsync(cbuf, 0, SZ_CBUF, stream);

        const _Float16* A16  = layer ? out16 : seq16;
        const int       K    = layer ? D1P : 512;
        const _Float16* WL   = layer ? wih116 : wih016;
        const float*    bfp  = bperm + (size_t)(layer * 2 + 0) * NPAD;
        const float*    bbp  = bperm + (size_t)(layer * 2 + 1) * NPAD;
        const _Float16* whhL = whh16 + (size_t)layer * 2 * WSL2;
        void*           yo   = layer ? d_out : (void*)out16;
        const int       y_ld = layer ? 1000 : D1P;
        const int       yF16 = layer ? 0 : 1;

        for (int ph = 0; ph < 8; ++ph) {
            const int t0f = ph * TCH;
            const int t0b = TT - TCH * (ph + 1);
            gemm16_kernel<<<dim3(32, 16, 2), 256, 0, stream>>>(
                A16, K, WL, bfp, bbp, gatesc, t0f, t0b);
            const int gstep0 = layer * TT + ph * TCH;
            lstm_phase_kernel<<<2 * NB2, 256, 0, stream>>>(
                gatesc, whhL, lengths, h16, cbuf, yo, y_ld, yF16,
                ph * TCH, gstep0, flags);
        }
    }
}

// Round 3
// 6620.515 us; speedup vs baseline: 2.6531x; 2.6531x over previous
//
#include <hip/hip_runtime.h>
#include <cstdint>
#include <cstddef>

// Problem constants
#define BB   64
#define TT   512
#define HH   500
#define G4H  2000   // 4*H
#define KPAD 512    // recurrent K padded 500 -> 512
#define TCH  64     // timesteps per phase
#define D1P  1024   // layer-1 input dim padded 1000 -> 1024
#define NPAD 2048   // gate rows padded 2000 -> 2048 (= 32 blocks * 64 rows)
#define UPB  16     // hidden units per recurrence block
#define NB2  32     // recurrence blocks per direction
#define WSL2 (32 * 64 * 512)   // per-dir fp16 recurrent weight slice elements

typedef _Float16 v8h __attribute__((ext_vector_type(8)));
typedef _Float16 v4h __attribute__((ext_vector_type(4)));
typedef float    v4f __attribute__((ext_vector_type(4)));

union F16x8 { unsigned long long u[2]; float4 f4; v8h h; };
union H16B  { _Float16 f; unsigned short u; };

__device__ __forceinline__ float sigm(float x) { return 1.f / (1.f + __expf(-x)); }
__device__ __forceinline__ float tanh_fast(float x) {
    float e = __expf(2.f * x);
    return 1.f - 2.f / (e + 1.f);
}

// async global->LDS, 16B per lane. LDS dest must be wave-linear (base + lane*16).
__device__ __forceinline__ void gload_lds16(const _Float16* src, _Float16* dst) {
    __builtin_amdgcn_global_load_lds(
        (const __attribute__((address_space(1))) void*)src,
        (__attribute__((address_space(3))) void*)dst, 16, 0, 0);
}

// Row permutation shared by all gate-side tensors:
//   n' = bi*64 + g*16 + j  <->  original gate row g*500 + (bi*16 + j)
//   valid iff u = bi*16 + j < 500

// ---- prep: W_hh [2000][500] fp32 -> fp16 slices [ld][bi(32)][r(64)][k(512)] ----
__global__ __launch_bounds__(256) void pad_whh16_kernel(
    const float* __restrict__ w0, const float* __restrict__ w1,
    const float* __restrict__ w2, const float* __restrict__ w3,
    _Float16* __restrict__ dst)
{
    int idx = blockIdx.x * 256 + threadIdx.x;   // exactly 4*32*64*512 threads
    int k = idx & 511;
    int t = idx >> 9;
    int r = t & 63;  t >>= 6;
    int bi = t & 31;
    int ld = t >> 5;
    int g = r >> 4, j = r & 15;
    int u = bi * UPB + j;
    const float* src = (ld == 0) ? w0 : (ld == 1) ? w1 : (ld == 2) ? w2 : w3;
    float val = (u < HH && k < HH) ? src[(size_t)(g * HH + u) * HH + k] : 0.f;
    dst[idx] = (_Float16)val;
}

// ---- prep: W_ih -> fp16, rows permuted, [dir][NPAD][1<<kshift] ----
__global__ __launch_bounds__(256) void pad_wih16_kernel(
    const float* __restrict__ wf, const float* __restrict__ wb,
    _Float16* __restrict__ dst, int ksrc, int kshift)
{
    int idx = blockIdx.x * 256 + threadIdx.x;
    int kdst = 1 << kshift;
    int k = idx & (kdst - 1);
    int n = (idx >> kshift) & (NPAD - 1);
    int d = idx >> (kshift + 11);
    int bi = n >> 6, r = n & 63, g = r >> 4, j = r & 15;
    int u = bi * UPB + j;
    const float* src = d ? wb : wf;
    float v = (u < HH && k < ksrc) ? src[(size_t)(g * HH + u) * ksrc + k] : 0.f;
    dst[idx] = (_Float16)v;
}

// ---- prep: bias -> permuted fp32 [4][NPAD] ----
__global__ __launch_bounds__(256) void bias_perm_kernel(
    const float* __restrict__ b0f_, const float* __restrict__ b0b_,
    const float* __restrict__ b1f_, const float* __restrict__ b1b_,
    float* __restrict__ dst)
{
    int idx = blockIdx.x * 256 + threadIdx.x;   // 4*2048
    int n = idx & (NPAD - 1);
    int ld = idx >> 11;
    int bi = n >> 6, r = n & 63, g = r >> 4, j = r & 15;
    int u = bi * UPB + j;
    const float* src = (ld == 0) ? b0f_ : (ld == 1) ? b0b_ : (ld == 2) ? b1f_ : b1b_;
    dst[idx] = (u < HH) ? src[g * HH + u] : 0.f;
}

// ---- prep: seqs fp32 -> fp16 (4 elems/thread) ----
__global__ __launch_bounds__(256) void f32to16x4_kernel(
    const float* __restrict__ src, _Float16* __restrict__ dst)
{
    int idx = blockIdx.x * 256 + threadIdx.x;
    float4 v = ((const float4*)src)[idx];
    v4h o;
    o[0] = (_Float16)v.x; o[1] = (_Float16)v.y;
    o[2] = (_Float16)v.z; o[3] = (_Float16)v.w;
    ((v4h*)dst)[idx] = o;
}

// ---- MFMA input-projection GEMM body (one 64-timestep chunk, both dirs) ----
#define BM 128
#define BN 128
#define BKG 64

__device__ __forceinline__ void gemm_body(
    int g, _Float16* smemh,
    const _Float16* __restrict__ A16, int K,
    const _Float16* __restrict__ W16,     // [2][NPAD][K], rows permuted
    const float* __restrict__ bf_, const float* __restrict__ bb_,
    float* __restrict__ gates, int t0f, int t0b)
{
    const int mtile = g & 31;
    const int ntile = (g >> 5) & 15;
    const int dir   = g >> 9;
    const int t0  = dir ? t0b : t0f;
    const _Float16* W = W16 + (size_t)dir * NPAD * K;
    const float* bias = dir ? bb_ : bf_;
    const int tid  = threadIdx.x;
    const int lane = tid & 63;
    const int wv = __builtin_amdgcn_readfirstlane(tid >> 6);
    const int wm = wv >> 1, wn = wv & 1;

    _Float16* Asm = smemh;               // [BM*BKG] 16 KB
    _Float16* Bsm = smemh + BM * BKG;    // [BN*BKG] 16 KB

    const _Float16* aPtr[4];
    const _Float16* bPtr[4];
    #pragma unroll
    for (int it = 0; it < 4; ++it) {
        const int s = tid + it * 256;
        const int row = s >> 3;
        const int kswz = ((s ^ row) & 7) << 3;       // (slot8 ^ (row&7)) * 8
        const int rg = mtile * BM + row;
        const int b = rg >> 6;
        const int t = t0 + (rg & 63);
        aPtr[it] = A16 + (size_t)(b * TT + t) * K + kswz;
        bPtr[it] = W + (size_t)(ntile * BN + row) * K + kswz;
    }

    v4f acc[4][4];
    #pragma unroll
    for (int mt = 0; mt < 4; ++mt)
        #pragma unroll
        for (int nt = 0; nt < 4; ++nt) acc[mt][nt] = (v4f)(0.f);

    for (int k0 = 0; k0 < K; k0 += BKG) {
        #pragma unroll
        for (int it = 0; it < 4; ++it) {
            gload_lds16(aPtr[it] + k0, &Asm[(tid + it * 256) * 8]);
            gload_lds16(bPtr[it] + k0, &Bsm[(tid + it * 256) * 8]);
        }
        __syncthreads();
        #pragma unroll
        for (int kk = 0; kk < 2; ++kk) {
            v8h af[4], bw[4];
            #pragma unroll
            for (int mt = 0; mt < 4; ++mt) {
                const int row = wm * 64 + mt * 16 + (lane & 15);
                const int slot = (kk * 4 + (lane >> 4)) ^ (row & 7);
                af[mt] = *(const v8h*)&Asm[row * BKG + slot * 8];
            }
            #pragma unroll
            for (int nt = 0; nt < 4; ++nt) {
                const int row = wn * 64 + nt * 16 + (lane & 15);
                const int slot = (kk * 4 + (lane >> 4)) ^ (row & 7);
                bw[nt] = *(const v8h*)&Bsm[row * BKG + slot * 8];
            }
            #pragma unroll
            for (int mt = 0; mt < 4; ++mt)
                #pragma unroll
                for (int nt = 0; nt < 4; ++nt)
                    acc[mt][nt] = __builtin_amdgcn_mfma_f32_16x16x32_f16(
                        af[mt], bw[nt], acc[mt][nt], 0, 0, 0);
        }
        __syncthreads();
    }

    float* gout = gates + (size_t)dir * (BB * TCH * NPAD);
    const int colBase = ntile * BN + wn * 64 + (lane & 15);
    const int rowBase = mtile * BM + wm * 64 + ((lane >> 4) * 4);
    #pragma unroll
    for (int nt = 0; nt < 4; ++nt) {
        const int n = colBase + nt * 16;
        const float bv = bias[n];
        #pragma unroll
        for (int mt = 0; mt < 4; ++mt) {
            const int r = rowBase + mt * 16;
            const int b = r >> 6;
            const int tl = r & 63;
            float* gp = gout + (size_t)(b * TCH + tl) * NPAD + n;
            #pragma unroll
            for (int i = 0; i < 4; ++i)
                gp[(size_t)i * NPAD] = acc[mt][nt][i] + bv;
        }
    }
}

// ---- standalone GEMM wrapper (phase 0 of each layer) ----
__global__ __launch_bounds__(256, 2) void gemm16_kernel(
    const _Float16* __restrict__ A16, int K,
    const _Float16* __restrict__ W16,
    const float* __restrict__ bf_, const float* __restrict__ bb_,
    float* __restrict__ gates, int t0f, int t0b)
{
    extern __shared__ _Float16 smemh[];
    gemm_body(blockIdx.x, smemh, A16, K, W16, bf_, bb_, gates, t0f, t0b);
}

// ---- fused phase kernel ----
// blocks 0..63: persistent recurrence for phase p (64 steps, both dirs).
//   Wave w owns batches 16w..16w+15 (all 64 gate rows). W_hh slice (64x512
//   fp16, 64 KB) staged in LDS once per phase, XOR-swizzled. Per step: 32
//   parallel coherent b64 A-loads + 64 ds_read_b128 B-frags + 64 MFMA;
//   epilogue fully in-register (lane owns unit lane&15 x 4 batches).
// blocks 64..1087 (if doGemm): input GEMM for phase p+1 into gatesN.
__global__ __launch_bounds__(256, 1) void fused_phase_kernel(
    const float*    __restrict__ gates,   // phase p: [dir][B][TCH][NPAD]
    const _Float16* __restrict__ whh16,   // layer base: [dir][bi][64][512]
    const int*      __restrict__ lengths,
    _Float16* __restrict__ h16,           // [dir][2][B][512] fp16
    float*    __restrict__ cbuf,          // [dir][B][KPAD] fp32
    void*     __restrict__ yout, int y_ld, int yF16,
    int s0, int gstep0,
    unsigned int* __restrict__ flags,     // [64] x 16 u32 (64B spacing)
    const _Float16* __restrict__ A16, int K,
    const _Float16* __restrict__ W16,
    const float* __restrict__ bfp, const float* __restrict__ bbp,
    float* __restrict__ gatesN, int nt0f, int nt0b, int doGemm)
{
    extern __shared__ _Float16 smemh[];   // 64 KB dynamic

    if (blockIdx.x >= 64) {
        if (doGemm)
            gemm_body(blockIdx.x - 64, smemh, A16, K, W16, bfp, bbp,
                      gatesN, nt0f, nt0b);
        return;
    }

    // ---------------- recurrence ----------------
    const int tid  = threadIdx.x;
    const int dir  = (blockIdx.x >= NB2) ? 1 : 0;
    const int bi   = blockIdx.x - dir * NB2;
    const int u0   = bi * UPB;
    const int lane = tid & 63;
    const int w    = __builtin_amdgcn_readfirstlane(tid >> 6);  // batch group

    _Float16* Wl = smemh;   // [64 rows][512 k] fp16, XOR-swizzled (16B slots)

    // stage W slice once per phase: LDS slot 'slot' (16B) holds
    // W[r = slot>>6][ ((slot&63) ^ (r&7)) * 8 .. +8 ]
    {
        const _Float16* wsrc = whh16 + (size_t)dir * WSL2 + (size_t)bi * 64 * 512;
        #pragma unroll
        for (int it = 0; it < 16; ++it) {
            const int slot = tid + it * 256;
            const int r = slot >> 6, sp = slot & 63;
            gload_lds16(wsrc + (size_t)r * 512 + ((sp ^ (r & 7)) << 3),
                        Wl + slot * 8);
        }
    }

    const int jn = lane & 15;        // unit within block (D col) / A-row idx
    const int hi = lane >> 4;        // 0..3
    const bool uval = (u0 + jn) < HH;
    const int b0 = w * 16 + hi * 4;  // first of this lane's 4 batches (D rows)

    int lenv[4];
    float cst[4], hpv[4];
    #pragma unroll
    for (int i = 0; i < 4; ++i) {
        const int b = b0 + i;
        lenv[i] = lengths[b];
        cst[i]  = cbuf[(size_t)(dir * BB + b) * KPAD + u0 + jn];
        hpv[i]  = (float)h16[((size_t)(dir * 2 + 0) * BB + b) * 512 + u0 + jn];
    }

    __syncthreads();   // W staged (drains global_load_lds)

    const float* gb = gates + (size_t)dir * (BB * TCH * NPAD) + bi * 64 + jn;

    for (int sl = 0; sl < TCH; ++sl) {
        const int s   = s0 + sl;
        const int par = s & 1;
        const int t   = dir ? (TT - 1 - s) : s;
        const int tl  = dir ? (TCH - 1 - sl) : sl;

        // A-frags: h of this wave's 16 batches; 32 independent coherent loads
        F16x8 av[16];
        {
            const char* hb = (const char*)(h16 + (size_t)(dir * 2 + par) * BB * 512);
            const size_t base = ((size_t)(w * 16 + jn) * 512 + hi * 8) * 2;
            #pragma unroll
            for (int kt = 0; kt < 16; ++kt) {
                const unsigned long long* p =
                    (const unsigned long long*)(hb + base + (size_t)kt * 64);
                av[kt].u[0] = __hip_atomic_load(p,     __ATOMIC_RELAXED, __HIP_MEMORY_SCOPE_AGENT);
                av[kt].u[1] = __hip_atomic_load(p + 1, __ATOMIC_RELAXED, __HIP_MEMORY_SCOPE_AGENT);
            }
        }

        // gate-x loads: 16 scalars (4 batches x 4 gates), lanes 0-15 coalesce
        float gx[4][4];   // [g][i]
        #pragma unroll
        for (int i = 0; i < 4; ++i) {
            const float* gp = gb + ((size_t)((b0 + i) * TCH + tl)) * NPAD;
            #pragma unroll
            for (int g = 0; g < 4; ++g) gx[g][i] = gp[g * 16];
        }

        // 64 MFMAs: 4 independent chains (gate g), depth 16 (kt)
        v4f acc[4];
        #pragma unroll
        for (int g = 0; g < 4; ++g) acc[g] = (v4f)(0.f);
        #pragma unroll
        for (int kt = 0; kt < 16; ++kt) {
            #pragma unroll
            for (int g = 0; g < 4; ++g) {
                const int r = g * 16 + jn;                    // B row (gate row)
                const int sphys = (kt * 4 + hi) ^ (jn & 7);   // swizzled 16B slot
                F16x8 bf; bf.f4 = *(const float4*)&Wl[r * 512 + sphys * 8];
                acc[g] = __builtin_amdgcn_mfma_f32_16x16x32_f16(
                    av[kt].h, bf.h, acc[g], 0, 0, 0);
            }
        }

        // in-register epilogue: lane owns (unit jn, batches b0..b0+3)
        float ysv[4];
        #pragma unroll
        for (int i = 0; i < 4; ++i) {
            const bool msk = (t < lenv[i]);
            const float p0 = acc[0][i] + gx[0][i];
            const float p1 = acc[1][i] + gx[1][i];
            const float p2 = acc[2][i] + gx[2][i];
            const float p3 = acc[3][i] + gx[3][i];
            const float ig = sigm(p0);
            const float fg = sigm(p1);
            const float gg = tanh_fast(p2);
            const float og = sigm(p3);
            const float cn = fg * cst[i] + ig * gg;
            const float hn = og * tanh_fast(cn);
            cst[i] = msk ? cn : cst[i];
            hpv[i] = msk ? hn : hpv[i];
            ysv[i] = msk ? hn : 0.f;
        }

        // y store + h publish (2B coherent stores; lanes 0-15 coalesce)
        if (uval) {
            #pragma unroll
            for (int i = 0; i < 4; ++i) {
                const int b = b0 + i;
                const size_t yoff = ((size_t)b * TT + t) * y_ld + dir * HH + u0 + jn;
                if (yF16) ((_Float16*)yout)[yoff] = (_Float16)ysv[i];
                else      ((float*)yout)[yoff]    = ysv[i];
                H16B hb16; hb16.f = (_Float16)hpv[i];
                __hip_atomic_store(
                    (unsigned short*)h16 +
                        ((size_t)(dir * 2 + (par ^ 1)) * BB + b) * 512 + u0 + jn,
                    hb16.u, __ATOMIC_RELAXED, __HIP_MEMORY_SCOPE_AGENT);
            }
        }

        __syncthreads();   // drains all waves' publish/y stores (vmcnt 0)

        // flag-array barrier: parallel arrival + parallel poll
        const unsigned int tgt = (unsigned int)(gstep0 + sl + 1);
        if (tid == 0)
            __hip_atomic_store(&flags[(dir * NB2 + bi) * 16], tgt,
                               __ATOMIC_RELAXED, __HIP_MEMORY_SCOPE_AGENT);
        if (tid < 64) {
            const int fi = lane & 31;
            for (;;) {
                unsigned int v = __hip_atomic_load(&flags[(dir * NB2 + fi) * 16],
                                                   __ATOMIC_RELAXED, __HIP_MEMORY_SCOPE_AGENT);
                if (__all(v >= tgt)) break;
                __builtin_amdgcn_s_sleep(2);
            }
        }
        __syncthreads();
    }

    // persist c (fp32) for next phase
    if (uval) {
        #pragma unroll
        for (int i = 0; i < 4; ++i)
            cbuf[(size_t)(dir * BB + b0 + i) * KPAD + u0 + jn] = cst[i];
    }
}

extern "C" void kernel_launch(void* const* d_in, const int* in_sizes, int n_in,
                              void* d_out, int out_size, void* d_ws, size_t ws_size,
                              hipStream_t stream)
{
    (void)in_sizes; (void)n_in; (void)out_size; (void)ws_size;

    const float* seqs    = (const float*)d_in[0];
    const int*   lengths = (const int*)  d_in[1];
    const float* W_ih0f  = (const float*)d_in[2];
    const float* W_hh0f  = (const float*)d_in[3];
    const float* b0f     = (const float*)d_in[4];
    const float* W_ih0b  = (const float*)d_in[5];
    const float* W_hh0b  = (const float*)d_in[6];
    const float* b0b     = (const float*)d_in[7];
    const float* W_ih1f  = (const float*)d_in[8];
    const float* W_hh1f  = (const float*)d_in[9];
    const float* b1f     = (const float*)d_in[10];
    const float* W_ih1b  = (const float*)d_in[11];
    const float* W_hh1b  = (const float*)d_in[12];
    const float* b1b     = (const float*)d_in[13];

    char* ws = (char*)d_ws;
    const size_t SZ_GATES = (size_t)2 * BB * TCH * NPAD * 4;  //  67,108,864 (x2)
    const size_t SZ_SEQ16 = (size_t)BB * TT * 512 * 2;        //  33,554,432
    const size_t SZ_OUT16 = (size_t)BB * TT * D1P * 2;        //  67,108,864
    const size_t SZ_WIH0  = (size_t)2 * NPAD * 512 * 2;       //   4,194,304
    const size_t SZ_WIH1  = (size_t)2 * NPAD * D1P * 2;       //   8,388,608
    const size_t SZ_WHH16 = (size_t)4 * WSL2 * 2;             //   8,388,608
    const size_t SZ_BPERM = (size_t)4 * NPAD * 4;             //      32,768
    const size_t SZ_H16   = (size_t)2 * 2 * BB * 512 * 2;     //     262,144
    const size_t SZ_CBUF  = (size_t)2 * BB * KPAD * 4;        //     262,144
    const size_t SZ_FLAGS = (size_t)64 * 16 * 4;              //       4,096

    size_t off = 0;
    float*     gatesA = (float*)(ws + off);     off += SZ_GATES;
    float*     gatesB = (float*)(ws + off);     off += SZ_GATES;
    _Float16*  seq16  = (_Float16*)(ws + off);  off += SZ_SEQ16;
    _Float16*  out16  = (_Float16*)(ws + off);  off += SZ_OUT16;
    _Float16*  wih016 = (_Float16*)(ws + off);  off += SZ_WIH0;
    _Float16*  wih116 = (_Float16*)(ws + off);  off += SZ_WIH1;
    _Float16*  whh16  = (_Float16*)(ws + off);  off += SZ_WHH16;
    float*     bperm  = (float*)(ws + off);     off += SZ_BPERM;
    _Float16*  h16    = (_Float16*)(ws + off);  off += SZ_H16;
    float*     cbuf   = (float*)(ws + off);     off += SZ_CBUF;
    unsigned int* flags = (unsigned int*)(ws + off);  off += SZ_FLAGS;

    // one-time prep
    pad_whh16_kernel<<<16384, 256, 0, stream>>>(W_hh0f, W_hh0b, W_hh1f, W_hh1b, whh16);
    pad_wih16_kernel<<<8192,  256, 0, stream>>>(W_ih0f, W_ih0b, wih016, 512, 9);
    pad_wih16_kernel<<<16384, 256, 0, stream>>>(W_ih1f, W_ih1b, wih116, 1000, 10);
    bias_perm_kernel<<<32,    256, 0, stream>>>(b0f, b0b, b1f, b1b, bperm);
    f32to16x4_kernel<<<16384, 256, 0, stream>>>(seqs, seq16);
    hipMemsetAsync(out16, 0, SZ_OUT16, stream);   // zeros k-pad cols 1000..1023
    hipMemsetAsync(flags, 0, SZ_FLAGS, stream);

    for (int layer = 0; layer < 2; ++layer) {
        hipMemsetAsync(h16, 0, SZ_H16, stream);
        hipMemsetAsync(cbuf, 0, SZ_CBUF, stream);

        const _Float16* A16  = layer ? out16 : seq16;
        const int       K    = layer ? D1P : 512;
        const _Float16* WL   = layer ? wih116 : wih016;
        const float*    bfp  = bperm + (size_t)(layer * 2 + 0) * NPAD;
        const float*    bbp  = bperm + (size_t)(layer * 2 + 1) * NPAD;
        const _Float16* whhL = whh16 + (size_t)layer * 2 * WSL2;
        void*           yo   = layer ? d_out : (void*)out16;
        const int       y_ld = layer ? 1000 : D1P;
        const int       yF16 = layer ? 0 : 1;

        // phase-0 GEMM standalone (for layer 1, out16 is complete by now)
        gemm16_kernel<<<1024, 256, 32768, stream>>>(
            A16, K, WL, bfp, bbp, gatesA, 0, TT - TCH);

        for (int ph = 0; ph < 8; ++ph) {
            float* gcur = (ph & 1) ? gatesB : gatesA;
            float* gnxt = (ph & 1) ? gatesA : gatesB;
            const int doG  = (ph < 7) ? 1 : 0;
            const int nt0f = (ph + 1) * TCH;
            const int nt0b = TT - TCH * (ph + 2);
            const int gstep0 = layer * TT + ph * TCH;
            fused_phase_kernel<<<doG ? 1088 : 64, 256, 65536, stream>>>(
                gcur, whhL, lengths, h16, cbuf, yo, y_ld, yF16,
                ph * TCH, gstep0, flags,
                A16, K, WL, bfp, bbp, gnxt, nt0f, nt0b, doG);
        }
    }
}

// Round 6
// 6470.581 us; speedup vs baseline: 2.7146x; 1.0232x over previous
//
#include <hip/hip_runtime.h>
#include <cstdint>
#include <cstddef>

// Problem constants
#define BB   64
#define TT   512
#define HH   500
#define G4H  2000   // 4*H
#define KPAD 512    // recurrent K padded 500 -> 512
#define TCH  64     // timesteps per phase
#define D1P  1024   // layer-1 input dim padded 1000 -> 1024
#define NPAD 2048   // gate rows padded 2000 -> 2048 (= 32 blocks * 64 rows)
#define UPB  16     // hidden units per recurrence block
#define NB2  32     // recurrence blocks per direction
#define WSL2 (32 * 64 * 512)   // per-dir fp16 recurrent weight slice elements

typedef _Float16 v8h __attribute__((ext_vector_type(8)));
typedef _Float16 v4h __attribute__((ext_vector_type(4)));
typedef float    v4f __attribute__((ext_vector_type(4)));

union F16x8 { unsigned long long u[2]; float4 f4; v8h h; };
union H16B  { _Float16 f; unsigned short u; };

__device__ __forceinline__ float sigm(float x) { return 1.f / (1.f + __expf(-x)); }
__device__ __forceinline__ float tanh_fast(float x) {
    float e = __expf(2.f * x);
    return 1.f - 2.f / (e + 1.f);
}

// async global->LDS, 16B per lane. LDS dest must be wave-linear (base + lane*16).
__device__ __forceinline__ void gload_lds16(const _Float16* src, _Float16* dst) {
    __builtin_amdgcn_global_load_lds(
        (const __attribute__((address_space(1))) void*)src,
        (__attribute__((address_space(3))) void*)dst, 16, 0, 0);
}

// Row permutation shared by all gate-side tensors:
//   n' = bi*64 + g*16 + j  <->  original gate row g*500 + (bi*16 + j)
//   valid iff u = bi*16 + j < 500

// ---- prep: W_hh [2000][500] fp32 -> fp16 slices [ld][bi(32)][r(64)][k(512)] ----
__global__ __launch_bounds__(256) void pad_whh16_kernel(
    const float* __restrict__ w0, const float* __restrict__ w1,
    const float* __restrict__ w2, const float* __restrict__ w3,
    _Float16* __restrict__ dst)
{
    int idx = blockIdx.x * 256 + threadIdx.x;   // exactly 4*32*64*512 threads
    int k = idx & 511;
    int t = idx >> 9;
    int r = t & 63;  t >>= 6;
    int bi = t & 31;
    int ld = t >> 5;
    int g = r >> 4, j = r & 15;
    int u = bi * UPB + j;
    const float* src = (ld == 0) ? w0 : (ld == 1) ? w1 : (ld == 2) ? w2 : w3;
    float val = (u < HH && k < HH) ? src[(size_t)(g * HH + u) * HH + k] : 0.f;
    dst[idx] = (_Float16)val;
}

// ---- prep: W_ih -> fp16, rows permuted, [dir][NPAD][1<<kshift] ----
__global__ __launch_bounds__(256) void pad_wih16_kernel(
    const float* __restrict__ wf, const float* __restrict__ wb,
    _Float16* __restrict__ dst, int ksrc, int kshift)
{
    int idx = blockIdx.x * 256 + threadIdx.x;
    int kdst = 1 << kshift;
    int k = idx & (kdst - 1);
    int n = (idx >> kshift) & (NPAD - 1);
    int d = idx >> (kshift + 11);
    int bi = n >> 6, r = n & 63, g = r >> 4, j = r & 15;
    int u = bi * UPB + j;
    const float* src = d ? wb : wf;
    float v = (u < HH && k < ksrc) ? src[(size_t)(g * HH + u) * ksrc + k] : 0.f;
    dst[idx] = (_Float16)v;
}

// ---- prep: bias -> permuted fp32 [4][NPAD] ----
__global__ __launch_bounds__(256) void bias_perm_kernel(
    const float* __restrict__ b0f_, const float* __restrict__ b0b_,
    const float* __restrict__ b1f_, const float* __restrict__ b1b_,
    float* __restrict__ dst)
{
    int idx = blockIdx.x * 256 + threadIdx.x;   // 4*2048
    int n = idx & (NPAD - 1);
    int ld = idx >> 11;
    int bi = n >> 6, r = n & 63, g = r >> 4, j = r & 15;
    int u = bi * UPB + j;
    const float* src = (ld == 0) ? b0f_ : (ld == 1) ? b0b_ : (ld == 2) ? b1f_ : b1b_;
    dst[idx] = (u < HH) ? src[g * HH + u] : 0.f;
}

// ---- prep: seqs fp32 -> fp16 (4 elems/thread) ----
__global__ __launch_bounds__(256) void f32to16x4_kernel(
    const float* __restrict__ src, _Float16* __restrict__ dst)
{
    int idx = blockIdx.x * 256 + threadIdx.x;
    float4 v = ((const float4*)src)[idx];
    v4h o;
    o[0] = (_Float16)v.x; o[1] = (_Float16)v.y;
    o[2] = (_Float16)v.z; o[3] = (_Float16)v.w;
    ((v4h*)dst)[idx] = o;
}

// ---- MFMA input-projection GEMM body (one 64-timestep chunk, both dirs) ----
#define BM 128
#define BN 128
#define BKG 64

__device__ __forceinline__ void gemm_body(
    int g, _Float16* smemh,
    const _Float16* __restrict__ A16, int K,
    const _Float16* __restrict__ W16,     // [2][NPAD][K], rows permuted
    const float* __restrict__ bf_, const float* __restrict__ bb_,
    float* __restrict__ gates, int t0f, int t0b)
{
    const int mtile = g & 31;
    const int ntile = (g >> 5) & 15;
    const int dir   = g >> 9;
    const int t0  = dir ? t0b : t0f;
    const _Float16* W = W16 + (size_t)dir * NPAD * K;
    const float* bias = dir ? bb_ : bf_;
    const int tid  = threadIdx.x;
    const int lane = tid & 63;
    const int wv = __builtin_amdgcn_readfirstlane(tid >> 6);
    const int wm = wv >> 1, wn = wv & 1;

    _Float16* Asm = smemh;               // [BM*BKG] 16 KB
    _Float16* Bsm = smemh + BM * BKG;    // [BN*BKG] 16 KB

    const _Float16* aPtr[4];
    const _Float16* bPtr[4];
    #pragma unroll
    for (int it = 0; it < 4; ++it) {
        const int s = tid + it * 256;
        const int row = s >> 3;
        const int kswz = ((s ^ row) & 7) << 3;       // (slot8 ^ (row&7)) * 8
        const int rg = mtile * BM + row;
        const int b = rg >> 6;
        const int t = t0 + (rg & 63);
        aPtr[it] = A16 + (size_t)(b * TT + t) * K + kswz;
        bPtr[it] = W + (size_t)(ntile * BN + row) * K + kswz;
    }

    v4f acc[4][4];
    #pragma unroll
    for (int mt = 0; mt < 4; ++mt)
        #pragma unroll
        for (int nt = 0; nt < 4; ++nt) acc[mt][nt] = (v4f)(0.f);

    for (int k0 = 0; k0 < K; k0 += BKG) {
        #pragma unroll
        for (int it = 0; it < 4; ++it) {
            gload_lds16(aPtr[it] + k0, &Asm[(tid + it * 256) * 8]);
            gload_lds16(bPtr[it] + k0, &Bsm[(tid + it * 256) * 8]);
        }
        __syncthreads();
        #pragma unroll
        for (int kk = 0; kk < 2; ++kk) {
            v8h af[4], bw[4];
            #pragma unroll
            for (int mt = 0; mt < 4; ++mt) {
                const int row = wm * 64 + mt * 16 + (lane & 15);
                const int slot = (kk * 4 + (lane >> 4)) ^ (row & 7);
                af[mt] = *(const v8h*)&Asm[row * BKG + slot * 8];
            }
            #pragma unroll
            for (int nt = 0; nt < 4; ++nt) {
                const int row = wn * 64 + nt * 16 + (lane & 15);
                const int slot = (kk * 4 + (lane >> 4)) ^ (row & 7);
                bw[nt] = *(const v8h*)&Bsm[row * BKG + slot * 8];
            }
            #pragma unroll
            for (int mt = 0; mt < 4; ++mt)
                #pragma unroll
                for (int nt = 0; nt < 4; ++nt)
                    acc[mt][nt] = __builtin_amdgcn_mfma_f32_16x16x32_f16(
                        af[mt], bw[nt], acc[mt][nt], 0, 0, 0);
        }
        __syncthreads();
    }

    float* gout = gates + (size_t)dir * (BB * TCH * NPAD);
    const int colBase = ntile * BN + wn * 64 + (lane & 15);
    const int rowBase = mtile * BM + wm * 64 + ((lane >> 4) * 4);
    #pragma unroll
    for (int nt = 0; nt < 4; ++nt) {
        const int n = colBase + nt * 16;
        const float bv = bias[n];
        #pragma unroll
        for (int mt = 0; mt < 4; ++mt) {
            const int r = rowBase + mt * 16;
            const int b = r >> 6;
            const int tl = r & 63;
            float* gp = gout + (size_t)(b * TCH + tl) * NPAD + n;
            #pragma unroll
            for (int i = 0; i < 4; ++i)
                gp[(size_t)i * NPAD] = acc[mt][nt][i] + bv;
        }
    }
}

// ---- standalone GEMM wrapper (phase 0 of each layer); static 32 KB LDS ----
__global__ __launch_bounds__(256, 2) void gemm16_kernel(
    const _Float16* __restrict__ A16, int K,
    const _Float16* __restrict__ W16,
    const float* __restrict__ bf_, const float* __restrict__ bb_,
    float* __restrict__ gates, int t0f, int t0b)
{
    __shared__ _Float16 smemg[BM * BKG + BN * BKG];   // 32 KB
    gemm_body(blockIdx.x, smemg, A16, K, W16, bf_, bb_, gates, t0f, t0b);
}

// ---- fused phase kernel (R3-proven protocol; static 96 KB LDS) ----
// Static 96 KB -> 1 block/CU: recurrence blocks (0..63) get exclusive CUs.
// Recurrence: wave w owns batches 16w..16w+15, all 64 gate rows. W_hh slice
// in LDS (64 KB, XOR-swizzled). Per step: 32 coherent b64 A-loads + 64 MFMA;
// in-register epilogue; flag store + wave-0 poll + release barrier EVERY step
// (exact R3 protocol); next-step gate-x prefetched between flag and poll.
__global__ __launch_bounds__(256, 1) void fused_phase_kernel(
    const float*    __restrict__ gates,   // phase p: [dir][B][TCH][NPAD]
    const _Float16* __restrict__ whh16,   // layer base: [dir][bi][64][512]
    const int*      __restrict__ lengths,
    _Float16* __restrict__ h16,           // [dir][2][B][512] fp16
    float*    __restrict__ cbuf,          // [dir][B][KPAD] fp32
    void*     __restrict__ yout, int y_ld, int yF16,
    int s0, int gstep0,
    unsigned int* __restrict__ flags,     // [64] x 16 u32 (64B spacing)
    const _Float16* __restrict__ A16, int K,
    const _Float16* __restrict__ W16,
    const float* __restrict__ bfp, const float* __restrict__ bbp,
    float* __restrict__ gatesN, int nt0f, int nt0b, int doGemm)
{
    __shared__ _Float16 smemh[49152];     // 96 KB static

    if (blockIdx.x >= 64) {
        if (doGemm)
            gemm_body(blockIdx.x - 64, smemh, A16, K, W16, bfp, bbp,
                      gatesN, nt0f, nt0b);
        return;
    }

    // ---------------- recurrence ----------------
    const int tid  = threadIdx.x;
    const int dir  = blockIdx.x >> 5;
    const int bi   = blockIdx.x & 31;
    const int u0   = bi * UPB;
    const int lane = tid & 63;
    const int w    = __builtin_amdgcn_readfirstlane(tid >> 6);  // batch group

    _Float16* Wl = smemh;   // [64 rows][512 k] fp16, XOR-swizzled (16B slots)

    // stage W slice once per phase
    {
        const _Float16* wsrc = whh16 + (size_t)dir * WSL2 + (size_t)bi * 64 * 512;
        #pragma unroll
        for (int it = 0; it < 16; ++it) {
            const int slot = tid + it * 256;
            const int r = slot >> 6, sp = slot & 63;
            gload_lds16(wsrc + (size_t)r * 512 + ((sp ^ (r & 7)) << 3),
                        Wl + slot * 8);
        }
    }

    const int jn = lane & 15;        // unit within block (D col) / A-row idx
    const int hi = lane >> 4;        // 0..3
    const bool uval = (u0 + jn) < HH;
    const int b0 = w * 16 + hi * 4;  // first of this lane's 4 batches (D rows)

    int lenv[4];
    float cst[4], hpv[4];
    #pragma unroll
    for (int i = 0; i < 4; ++i) {
        const int b = b0 + i;
        lenv[i] = lengths[b];
        cst[i]  = cbuf[(size_t)(dir * BB + b) * KPAD + u0 + jn];
        hpv[i]  = (float)h16[((size_t)(dir * 2 + 0) * BB + b) * 512 + u0 + jn];
    }

    __syncthreads();   // W staged (drains global_load_lds)

    const float* gb = gates + (size_t)dir * (BB * TCH * NPAD) + bi * 64 + jn;

    // gate-x for step 0
    float gxv[4][4];   // [g][i]
    {
        const int tl0 = dir ? (TCH - 1) : 0;
        #pragma unroll
        for (int i = 0; i < 4; ++i) {
            const float* gp = gb + ((size_t)((b0 + i) * TCH + tl0)) * NPAD;
            #pragma unroll
            for (int g = 0; g < 4; ++g) gxv[g][i] = gp[g * 16];
        }
    }

    for (int sl = 0; sl < TCH; ++sl) {
        const int s   = s0 + sl;
        const int par = s & 1;
        const int t   = dir ? (TT - 1 - s) : s;

        // A-frags: h of this wave's 16 batches; 32 independent coherent loads
        F16x8 av[16];
        {
            const char* hb = (const char*)(h16 + (size_t)(dir * 2 + par) * BB * 512);
            const size_t base = ((size_t)(w * 16 + jn) * 512 + hi * 8) * 2;
            #pragma unroll
            for (int kt = 0; kt < 16; ++kt) {
                const unsigned long long* p =
                    (const unsigned long long*)(hb + base + (size_t)kt * 64);
                av[kt].u[0] = __hip_atomic_load(p,     __ATOMIC_RELAXED, __HIP_MEMORY_SCOPE_AGENT);
                av[kt].u[1] = __hip_atomic_load(p + 1, __ATOMIC_RELAXED, __HIP_MEMORY_SCOPE_AGENT);
            }
        }

        // 64 MFMAs: 4 independent chains (gate g), depth 16 (kt)
        v4f acc[4];
        #pragma unroll
        for (int g = 0; g < 4; ++g) acc[g] = (v4f)(0.f);
        #pragma unroll
        for (int kt = 0; kt < 16; ++kt) {
            #pragma unroll
            for (int g = 0; g < 4; ++g) {
                const int r = g * 16 + jn;                    // B row (gate row)
                const int sphys = (kt * 4 + hi) ^ (jn & 7);   // swizzled 16B slot
                F16x8 bf; bf.f4 = *(const float4*)&Wl[r * 512 + sphys * 8];
                acc[g] = __builtin_amdgcn_mfma_f32_16x16x32_f16(
                    av[kt].h, bf.h, acc[g], 0, 0, 0);
            }
        }

        // in-register epilogue: lane owns (unit jn, batches b0..b0+3)
        float ysv[4];
        #pragma unroll
        for (int i = 0; i < 4; ++i) {
            const bool msk = (t < lenv[i]);
            const float p0 = acc[0][i] + gxv[0][i];
            const float p1 = acc[1][i] + gxv[1][i];
            const float p2 = acc[2][i] + gxv[2][i];
            const float p3 = acc[3][i] + gxv[3][i];
            const float ig = sigm(p0);
            const float fg = sigm(p1);
            const float gg = tanh_fast(p2);
            const float og = sigm(p3);
            const float cn = fg * cst[i] + ig * gg;
            const float hn = og * tanh_fast(cn);
            cst[i] = msk ? cn : cst[i];
            hpv[i] = msk ? hn : hpv[i];
            ysv[i] = msk ? hn : 0.f;
        }

        // h publish first (critical path), then y store
        if (uval) {
            #pragma unroll
            for (int i = 0; i < 4; ++i) {
                const int b = b0 + i;
                H16B hb16; hb16.f = (_Float16)hpv[i];
                __hip_atomic_store(
                    (unsigned short*)h16 +
                        ((size_t)(dir * 2 + (par ^ 1)) * BB + b) * 512 + u0 + jn,
                    hb16.u, __ATOMIC_RELAXED, __HIP_MEMORY_SCOPE_AGENT);
            }
            #pragma unroll
            for (int i = 0; i < 4; ++i) {
                const int b = b0 + i;
                const size_t yoff = ((size_t)b * TT + t) * y_ld + dir * HH + u0 + jn;
                if (yF16) ((_Float16*)yout)[yoff] = (_Float16)ysv[i];
                else      ((float*)yout)[yoff]    = ysv[i];
            }
        }

        __syncthreads();   // drains all waves' publish/y stores (vmcnt 0)

        // flag-array barrier (R3 protocol): arrival store, wave-0 poll,
        // release barrier. Next-step gate-x prefetched under the poll.
        const unsigned int tgt = (unsigned int)(gstep0 + sl + 1);
        if (tid == 0)
            __hip_atomic_store(&flags[(dir * NB2 + bi) * 16], tgt,
                               __ATOMIC_RELAXED, __HIP_MEMORY_SCOPE_AGENT);

        float gxn[4][4];
        const bool hasNext = (sl + 1 < TCH);
        if (hasNext) {
            const int tln = dir ? (TCH - 2 - sl) : (sl + 1);
            #pragma unroll
            for (int i = 0; i < 4; ++i) {
                const float* gp = gb + ((size_t)((b0 + i) * TCH + tln)) * NPAD;
                #pragma unroll
                for (int g = 0; g < 4; ++g) gxn[g][i] = gp[g * 16];
            }
        }
        asm volatile("" ::: "memory");

        if (tid < 64) {
            const int fi = lane & 31;
            const unsigned int* fp = flags + (size_t)(dir * NB2 + fi) * 16;
            for (;;) {
                unsigned int v = __hip_atomic_load(fp, __ATOMIC_RELAXED,
                                                   __HIP_MEMORY_SCOPE_AGENT);
                if (__all(v >= tgt)) break;
                __builtin_amdgcn_s_sleep(1);
            }
        }
        __syncthreads();   // release whole block

        if (hasNext) {
            #pragma unroll
            for (int g = 0; g < 4; ++g)
                #pragma unroll
                for (int i = 0; i < 4; ++i) gxv[g][i] = gxn[g][i];
        }
    }

    // persist c (fp32) for next phase
    if (uval) {
        #pragma unroll
        for (int i = 0; i < 4; ++i)
            cbuf[(size_t)(dir * BB + b0 + i) * KPAD + u0 + jn] = cst[i];
    }
}

extern "C" void kernel_launch(void* const* d_in, const int* in_sizes, int n_in,
                              void* d_out, int out_size, void* d_ws, size_t ws_size,
                              hipStream_t stream)
{
    (void)in_sizes; (void)n_in; (void)out_size; (void)ws_size;

    const float* seqs    = (const float*)d_in[0];
    const int*   lengths = (const int*)  d_in[1];
    const float* W_ih0f  = (const float*)d_in[2];
    const float* W_hh0f  = (const float*)d_in[3];
    const float* b0f     = (const float*)d_in[4];
    const float* W_ih0b  = (const float*)d_in[5];
    const float* W_hh0b  = (const float*)d_in[6];
    const float* b0b     = (const float*)d_in[7];
    const float* W_ih1f  = (const float*)d_in[8];
    const float* W_hh1f  = (const float*)d_in[9];
    const float* b1f     = (const float*)d_in[10];
    const float* W_ih1b  = (const float*)d_in[11];
    const float* W_hh1b  = (const float*)d_in[12];
    const float* b1b     = (const float*)d_in[13];

    char* ws = (char*)d_ws;
    const size_t SZ_GATES = (size_t)2 * BB * TCH * NPAD * 4;  //  67,108,864 (x2)
    const size_t SZ_SEQ16 = (size_t)BB * TT * 512 * 2;        //  33,554,432
    const size_t SZ_OUT16 = (size_t)BB * TT * D1P * 2;        //  67,108,864
    const size_t SZ_WIH0  = (size_t)2 * NPAD * 512 * 2;       //   4,194,304
    const size_t SZ_WIH1  = (size_t)2 * NPAD * D1P * 2;       //   8,388,608
    const size_t SZ_WHH16 = (size_t)4 * WSL2 * 2;             //   8,388,608
    const size_t SZ_BPERM = (size_t)4 * NPAD * 4;             //      32,768
    const size_t SZ_H16   = (size_t)2 * 2 * BB * 512 * 2;     //     262,144
    const size_t SZ_CBUF  = (size_t)2 * BB * KPAD * 4;        //     262,144
    const size_t SZ_FLAGS = (size_t)64 * 16 * 4;              //       4,096

    size_t off = 0;
    float*     gatesA = (float*)(ws + off);     off += SZ_GATES;
    float*     gatesB = (float*)(ws + off);     off += SZ_GATES;
    _Float16*  seq16  = (_Float16*)(ws + off);  off += SZ_SEQ16;
    _Float16*  out16  = (_Float16*)(ws + off);  off += SZ_OUT16;
    _Float16*  wih016 = (_Float16*)(ws + off);  off += SZ_WIH0;
    _Float16*  wih116 = (_Float16*)(ws + off);  off += SZ_WIH1;
    _Float16*  whh16  = (_Float16*)(ws + off);  off += SZ_WHH16;
    float*     bperm  = (float*)(ws + off);     off += SZ_BPERM;
    _Float16*  h16    = (_Float16*)(ws + off);  off += SZ_H16;
    float*     cbuf   = (float*)(ws + off);     off += SZ_CBUF;
    unsigned int* flags = (unsigned int*)(ws + off);  off += SZ_FLAGS;

    // one-time prep
    pad_whh16_kernel<<<16384, 256, 0, stream>>>(W_hh0f, W_hh0b, W_hh1f, W_hh1b, whh16);
    pad_wih16_kernel<<<8192,  256, 0, stream>>>(W_ih0f, W_ih0b, wih016, 512, 9);
    pad_wih16_kernel<<<16384, 256, 0, stream>>>(W_ih1f, W_ih1b, wih116, 1000, 10);
    bias_perm_kernel<<<32,    256, 0, stream>>>(b0f, b0b, b1f, b1b, bperm);
    f32to16x4_kernel<<<16384, 256, 0, stream>>>(seqs, seq16);
    hipMemsetAsync(out16, 0, SZ_OUT16, stream);   // zeros k-pad cols 1000..1023
    hipMemsetAsync(flags, 0, SZ_FLAGS, stream);

    for (int layer = 0; layer < 2; ++layer) {
        hipMemsetAsync(h16, 0, SZ_H16, stream);
        hipMemsetAsync(cbuf, 0, SZ_CBUF, stream);

        const _Float16* A16  = layer ? out16 : seq16;
        const int       K    = layer ? D1P : 512;
        const _Float16* WL   = layer ? wih116 : wih016;
        const float*    bfp  = bperm + (size_t)(layer * 2 + 0) * NPAD;
        const float*    bbp  = bperm + (size_t)(layer * 2 + 1) * NPAD;
        const _Float16* whhL = whh16 + (size_t)layer * 2 * WSL2;
        void*           yo   = layer ? d_out : (void*)out16;
        const int       y_ld = layer ? 1000 : D1P;
        const int       yF16 = layer ? 0 : 1;

        // phase-0 GEMM standalone (for layer 1, out16 is complete by now)
        gemm16_kernel<<<1024, 256, 0, stream>>>(
            A16, K, WL, bfp, bbp, gatesA, 0, TT - TCH);

        for (int ph = 0; ph < 8; ++ph) {
            float* gcur = (ph & 1) ? gatesB : gatesA;
            float* gnxt = (ph & 1) ? gatesA : gatesB;
            const int doG  = (ph < 7) ? 1 : 0;
            const int nt0f = (ph + 1) * TCH;
            const int nt0b = TT - TCH * (ph + 2);
            const int gstep0 = layer * TT + ph * TCH;
            fused_phase_kernel<<<doG ? 1088 : 64, 256, 0, stream>>>(
                gcur, whhL, lengths, h16, cbuf, yo, y_ld, yF16,
                ph * TCH, gstep0, flags,
                A16, K, WL, bfp, bbp, gnxt, nt0f, nt0b, doG);
        }
    }
}